// Round 20
// baseline (309.100 us; speedup 1.0000x reference)
//
#include <hip/hip_runtime.h>
#include <hip/hip_bf16.h>
#include <hip/hip_fp8.h>
#include <cmath>

#define NN 30000
#define KK 25
#define IN_F 64
#define FEAT 32
#define HH 128
#define OUTF 64
#define EE 480000
#define NPAGE 469              // dst pages of 64 nodes
#define NB (8 * NPAGE)         // sort buckets
#define LUTN 4096
#define NT32 1875              // 32-edge tiles per XCD (8*1875*32 = 480000 = EE)
#define L1BLK (NN / 8)         // 3750 layer1 node blocks
#define SCBLK ((EE / 8 + 255) / 256)  // 235 scatter blocks fused into layer1

typedef __attribute__((ext_vector_type(8))) _Float16 fp16x8;
typedef __attribute__((ext_vector_type(2))) _Float16 h2v;
typedef __attribute__((ext_vector_type(16))) float f32x16;

__device__ inline float u2f(unsigned u) { return __builtin_bit_cast(float, u); }
__device__ inline unsigned short f2h(float f) {
    _Float16 h = (_Float16)f;
    return __builtin_bit_cast(unsigned short, h);
}
__device__ inline float blo(unsigned u) { return u2f(u << 16); }
__device__ inline float bhi(unsigned u) { return u2f(u & 0xffff0000u); }

// fp8 e4m3 (OCP) encode/decode — HW paths on gfx950
__device__ inline unsigned char f2f8(float v) {
    __hip_fp8_e4m3 h(v);
    return (unsigned char)h.__x;
}
template <int S0>
__device__ inline float f8d(unsigned u) {
    return __builtin_amdgcn_cvt_f32_fp8(u, S0);
}

// packed fp16: relu(a + b) on 2 lanes
__device__ inline unsigned hrelu2(unsigned a, unsigned b) {
    h2v x = __builtin_bit_cast(h2v, a);
    h2v y = __builtin_bit_cast(h2v, b);
    h2v s = x + y;
    h2v z = {(_Float16)0.f, (_Float16)0.f};
    h2v r = __builtin_elementwise_max(s, z);
    return __builtin_bit_cast(unsigned, r);
}

__device__ inline float lut_eval(const float* __restrict__ lut, float dm) {
    float tt = dm * (float)LUTN;
    int i0 = (int)tt;
    i0 = i0 < 0 ? 0 : (i0 > LUTN - 1 ? LUTN - 1 : i0);
    float f = tt - (float)i0;
    float l0 = lut[i0];
    return fmaf(lut[i0 + 1] - l0, f, l0);
}

// ---------------- K0: fused prep ----------------
__global__ void k_prep(const float* __restrict__ x,
                       const float* __restrict__ w_pre, const float* __restrict__ b_pre,
                       const float* __restrict__ l1wh, const float* __restrict__ l1bh,
                       const float* __restrict__ ffw2, const float* __restrict__ ffw1,
                       const float* __restrict__ l2wh,
                       const float* __restrict__ l1w1, const float* __restrict__ l1b1,
                       const float* __restrict__ l1w2, const float* __restrict__ l1b2,
                       const float* __restrict__ l2w1, const float* __restrict__ l2b1,
                       const float* __restrict__ l2w2, const float* __restrict__ l2b2,
                       unsigned* __restrict__ hist,
                       float* __restrict__ lut1, float* __restrict__ lut2,
                       unsigned short* __restrict__ xh, unsigned short* __restrict__ xl,
                       float* __restrict__ bfuse, unsigned short* __restrict__ wt,
                       unsigned short* __restrict__ wt1,
                       unsigned short* __restrict__ wt2h, unsigned short* __restrict__ wt2l,
                       unsigned short* __restrict__ wfh, unsigned short* __restrict__ wfl) {
    int gid = blockIdx.x * 256 + threadIdx.x;
    if (gid < NB) { hist[gid] = 0u; return; }
    gid -= NB;
    if (gid < 2 * (LUTN + 1)) {
        int which = gid / (LUTN + 1);
        int i = gid % (LUTN + 1);
        float dm = (float)i * (1.0f / (float)LUTN);
        const float* w1 = which ? l2w1 : l1w1;
        const float* b1 = which ? l2b1 : l1b1;
        const float* w2 = which ? l2w2 : l1w2;
        const float* b2 = which ? l2b2 : l1b2;
        float a = 0.f;
        for (int h = 0; h < HH; ++h)
            a = fmaf(fmaxf(fmaf(dm, w1[h], b1[h]), 0.f), w2[h], a);
        (which ? lut2 : lut1)[i] = a + b2[0];
        return;
    }
    gid -= 2 * (LUTN + 1);
    if (gid < NN * IN_F / 8) {
        int i = gid * 8;
        unsigned short vh[8], vl[8];
#pragma unroll
        for (int j = 0; j < 8; ++j) {
            float v = x[i + j];
            _Float16 hi = (_Float16)v;
            vh[j] = __builtin_bit_cast(unsigned short, hi);
            vl[j] = f2h((v - (float)hi) * 1024.f);
        }
        *(uint4*)(xh + i) = *(uint4*)vh;
        *(uint4*)(xl + i) = *(uint4*)vl;
        return;
    }
    gid -= NN * IN_F / 8;
    if (gid < 256) {
        int half = gid >> 7, h = gid & 127;
        const float* wh = l1wh + half * FEAT * HH + h;
        float acc = (half == 1) ? l1bh[h] : 0.f;
#pragma unroll
        for (int c = 0; c < FEAT; ++c) acc = fmaf(b_pre[c], wh[c * HH], acc);
        bfuse[gid] = acc;
    } else if (gid < 16640) {
        int i = gid - 256;
        int k = i >> 6, c = i & 63;
        wt[c * 256 + k] = f2h(ffw2[i]);
    } else if (gid < 82176) {
        int i = gid - 16640;
        int c = i >> 7, j = i & 127;
        float v = (c < 256) ? ffw1[j * 256 + c] : ffw1[(128 + j) * 256 + (c - 256)];
        wt1[c * 128 + j] = f2h(v);
    } else if (gid < 114944) {
        int i = gid - 82176;
        int c = i >> 7, j = i & 127;
        float v = (c < 128) ? l2wh[j * 128 + c] : l2wh[(128 + j) * 128 + (c - 128)];
        _Float16 hi = (_Float16)v;
        wt2h[c * 128 + j] = __builtin_bit_cast(unsigned short, hi);
        wt2l[c * 128 + j] = f2h((v - (float)hi) * 1024.f);
    } else if (gid < 131328) {
        int i = gid - 114944;
        int cc = i >> 6, j = i & 63;
        const float* wrow = w_pre + j * FEAT;
        float acc = 0.f;
#pragma unroll
        for (int c = 0; c < FEAT; ++c) {
            float wh = (cc < 128) ? l1wh[c * HH + cc] : l1wh[(FEAT + c) * HH + (cc - 128)];
            acc = fmaf(wrow[c], wh, acc);
        }
        _Float16 hi = (_Float16)acc;
        wfh[cc * 64 + j] = __builtin_bit_cast(unsigned short, hi);
        wfl[cc * 64 + j] = f2h((acc - (float)hi) * 1024.f);
    }
}

// ---------------- K0b: fused d-LUT eval + edge histogram ----------------
#define DL_N (NN * KK / 4)
__global__ void k_dlut_hist(const float* __restrict__ dmax, const float* __restrict__ lut1,
                            const float* __restrict__ lut2,
                            float* __restrict__ d1, float* __restrict__ d2,
                            const int* __restrict__ ei, unsigned* __restrict__ hist) {
    int gid = blockIdx.x * 256 + threadIdx.x;
    if (gid < DL_N) {
        int i = gid * 4;
        float4 dm = *(const float4*)(dmax + i);
        float4 o1, o2;
        o1.x = lut_eval(lut1, dm.x); o1.y = lut_eval(lut1, dm.y);
        o1.z = lut_eval(lut1, dm.z); o1.w = lut_eval(lut1, dm.w);
        o2.x = lut_eval(lut2, dm.x); o2.y = lut_eval(lut2, dm.y);
        o2.z = lut_eval(lut2, dm.z); o2.w = lut_eval(lut2, dm.w);
        *(float4*)(d1 + i) = o1;
        *(float4*)(d2 + i) = o2;
        return;
    }
    int base = (gid - DL_N) * 8;
    if (base >= EE) return;
    int4 s0 = *(const int4*)(ei + base);
    int4 s1 = *(const int4*)(ei + base + 4);
    int4 dd0 = *(const int4*)(ei + EE + base);
    int4 dd1 = *(const int4*)(ei + EE + base + 4);
    int ss[8] = {s0.x, s0.y, s0.z, s0.w, s1.x, s1.y, s1.z, s1.w};
    int dd[8] = {dd0.x, dd0.y, dd0.z, dd0.w, dd1.x, dd1.y, dd1.z, dd1.w};
#pragma unroll
    for (int j = 0; j < 8; ++j) {
        int key = (ss[j] * 8 / NN) * NPAGE + (dd[j] >> 6);
        atomicAdd(&hist[key], 1u);
    }
}

// ---------------- Unified node GEMM via split-fp16 MFMA; G out = fp8 e4m3 ----------------
template <int KD>
__global__ __launch_bounds__(256) void k_nodegemm(
    const unsigned short* __restrict__ Ah, const unsigned short* __restrict__ Al,
    const unsigned short* __restrict__ Wh, const unsigned short* __restrict__ Wl,
    const float* __restrict__ gbias, const float* __restrict__ sbias,
    unsigned char* __restrict__ Gb8, float* __restrict__ S,
    const unsigned* __restrict__ hist, unsigned* __restrict__ cursor, int nodeBlocks) {
    if (hist && blockIdx.x >= (unsigned)nodeBlocks) {
        int l = threadIdx.x;
        if (l >= 64) return;
        const int PER = 59;
        unsigned tot = 0;
        for (int j = 0; j < PER; ++j) {
            int i = l * PER + j;
            if (i < NB) tot += hist[i];
        }
        unsigned run = tot;
#pragma unroll
        for (int off = 1; off < 64; off <<= 1) {
            unsigned u = __shfl_up(run, off, 64);
            if (l >= off) run += u;
        }
        unsigned base = run - tot;
        for (int j = 0; j < PER; ++j) {
            int i = l * PER + j;
            if (i < NB) {
                cursor[i] = base;
                base += hist[i];
            }
        }
        return;
    }
    int t = threadIdx.x;
    int l = t & 63, w = t >> 6;
    int c = l & 31, kh = l >> 5;
    int nb = blockIdx.x * 32;
    int na = nb + c;
    if (na >= NN) na = NN - 1;
    fp16x8 afh[KD / 16], afl[KD / 16];
#pragma unroll
    for (int kt = 0; kt < KD / 16; ++kt) {
        afh[kt] = *(const fp16x8*)(Ah + na * KD + kt * 16 + kh * 8);
        afl[kt] = *(const fp16x8*)(Al + na * KD + kt * 16 + kh * 8);
    }
    f32x16 acch0, acch1, accl0, accl1;
#pragma unroll
    for (int i = 0; i < 16; ++i) { acch0[i] = 0.f; acch1[i] = 0.f; accl0[i] = 0.f; accl1[i] = 0.f; }
    int cb0 = w * 64, cb1 = w * 64 + 32;
#pragma unroll
    for (int kt = 0; kt < KD / 16; ++kt) {
        fp16x8 b0h = *(const fp16x8*)(Wh + (cb0 + c) * KD + kt * 16 + kh * 8);
        fp16x8 b0l = *(const fp16x8*)(Wl + (cb0 + c) * KD + kt * 16 + kh * 8);
        fp16x8 b1h = *(const fp16x8*)(Wh + (cb1 + c) * KD + kt * 16 + kh * 8);
        fp16x8 b1l = *(const fp16x8*)(Wl + (cb1 + c) * KD + kt * 16 + kh * 8);
        acch0 = __builtin_amdgcn_mfma_f32_32x32x16_f16(afh[kt], b0h, acch0, 0, 0, 0);
        accl0 = __builtin_amdgcn_mfma_f32_32x32x16_f16(afh[kt], b0l, accl0, 0, 0, 0);
        accl0 = __builtin_amdgcn_mfma_f32_32x32x16_f16(afl[kt], b0h, accl0, 0, 0, 0);
        acch1 = __builtin_amdgcn_mfma_f32_32x32x16_f16(afh[kt], b1h, acch1, 0, 0, 0);
        accl1 = __builtin_amdgcn_mfma_f32_32x32x16_f16(afh[kt], b1l, accl1, 0, 0, 0);
        accl1 = __builtin_amdgcn_mfma_f32_32x32x16_f16(afl[kt], b1h, accl1, 0, 0, 0);
    }
    const float inv1024 = 1.0f / 1024.0f;
#pragma unroll
    for (int half = 0; half < 2; ++half) {
        int col = (half ? cb1 : cb0) + c;
        bool isG = col < HH;
        float gb_ = (isG && gbias) ? gbias[col] : 0.f;
        float sb_ = (!isG) ? sbias[col - HH] : 0.f;
#pragma unroll
        for (int r = 0; r < 16; ++r) {
            int row = (r & 3) + 8 * (r >> 2) + 4 * kh;
            int n = nb + row;
            float v = half ? (acch1[r] + accl1[r] * inv1024)
                           : (acch0[r] + accl0[r] * inv1024);
            if (n < NN) {
                if (isG) Gb8[n * HH + col] = f2f8(v + gb_);
                else S[n * HH + (col - HH)] = v + sb_;
            }
        }
    }
}

// ---------------- K4: layer1, 2 nodes/WAVE, fp8 G gathers; fused edge scatter ----------------
__global__ void k_layer1(const unsigned* __restrict__ G8, const float* __restrict__ S1,
                         const float* __restrict__ d1, const int* __restrict__ amax,
                         uint2* __restrict__ hh, uint2* __restrict__ hl,
                         const int* __restrict__ ei, unsigned* __restrict__ cursor,
                         uint4* __restrict__ sedge) {
    if (blockIdx.x >= L1BLK) {
        int base = ((blockIdx.x - L1BLK) * 256 + threadIdx.x) * 8;
        if (base >= EE) return;
        int4 s0 = *(const int4*)(ei + base);
        int4 s1 = *(const int4*)(ei + base + 4);
        int4 d0 = *(const int4*)(ei + EE + base);
        int4 dd1 = *(const int4*)(ei + EE + base + 4);
        int ss[8] = {s0.x, s0.y, s0.z, s0.w, s1.x, s1.y, s1.z, s1.w};
        int dd[8] = {d0.x, d0.y, d0.z, d0.w, dd1.x, dd1.y, dd1.z, dd1.w};
        unsigned pp[8];
#pragma unroll
        for (int j = 0; j < 8; ++j) {
            int key = (ss[j] * 8 / NN) * NPAGE + (dd[j] >> 6);
            pp[j] = atomicAdd(&cursor[key], 1u);
        }
#pragma unroll
        for (int j = 0; j < 8; ++j)
            sedge[pp[j]] = make_uint4((unsigned)ss[j], (unsigned)dd[j], (unsigned)(base + j), 0u);
        return;
    }
    int t = threadIdx.x;
    int s = t & 31;
    int n = blockIdx.x * 8 + (t >> 5);
    float4 sv = *(const float4*)(S1 + n * HH + 4 * s);
    const int* arow = amax + n * KK;
    const float* drow = d1 + n * KK;
    unsigned gvv[KK];
#pragma unroll
    for (int k = 0; k < KK; ++k) gvv[k] = G8[(size_t)arow[k] * 32 + s];
    float dk_[KK];
#pragma unroll
    for (int k = 0; k < KK; ++k) dk_[k] = drow[k];
    float a0 = 0.f, a1 = 0.f, a2 = 0.f, a3 = 0.f;
#pragma unroll
    for (int k = 0; k < KK; ++k) {
        float d = dk_[k];
        unsigned g = gvv[k];
        a0 += fmaxf(fmaf(d, f8d<0>(g), sv.x), 0.f);
        a1 += fmaxf(fmaf(d, f8d<1>(g), sv.y), 0.f);
        a2 += fmaxf(fmaf(d, f8d<2>(g), sv.z), 0.f);
        a3 += fmaxf(fmaf(d, f8d<3>(g), sv.w), 0.f);
    }
    a0 *= 0.04f; a1 *= 0.04f; a2 *= 0.04f; a3 *= 0.04f;
    _Float16 h0 = (_Float16)a0, h1v = (_Float16)a1, h2v_ = (_Float16)a2, h3 = (_Float16)a3;
    uint2 oh, ol;
    oh.x = (unsigned)__builtin_bit_cast(unsigned short, h0) |
           ((unsigned)__builtin_bit_cast(unsigned short, h1v) << 16);
    oh.y = (unsigned)__builtin_bit_cast(unsigned short, h2v_) |
           ((unsigned)__builtin_bit_cast(unsigned short, h3) << 16);
    ol.x = (unsigned)f2h((a0 - (float)h0) * 1024.f) |
           ((unsigned)f2h((a1 - (float)h1v) * 1024.f) << 16);
    ol.y = (unsigned)f2h((a2 - (float)h2v_) * 1024.f) |
           ((unsigned)f2h((a3 - (float)h3) * 1024.f) << 16);
    hh[(size_t)n * 32 + s] = oh;
    hl[(size_t)n * 32 + s] = ol;
}

// ---------------- K6: layer2, 2 nodes/WAVE, fp8 G gathers ----------------
__global__ __launch_bounds__(256) void k_xpos2(
    const unsigned* __restrict__ G8, const float* __restrict__ S2,
    const float* __restrict__ d2, const int* __restrict__ amax,
    const float* __restrict__ wp, const float* __restrict__ bp,
    const float* __restrict__ wlin, const float* __restrict__ blin,
    uint2* __restrict__ hlu2) {
    int t = threadIdx.x;
    int s = t & 31;
    int n = blockIdx.x * 8 + (t >> 5);
    float4 sv = *(const float4*)(S2 + n * HH + 4 * s);
    float4 wpv = *(const float4*)(wp + 4 * s);
    const int* arow = amax + n * KK;
    const float* drow = d2 + n * KK;
    unsigned gvv[KK];
#pragma unroll
    for (int k = 0; k < KK; ++k) gvv[k] = G8[(size_t)arow[k] * 32 + s];
    float dk_[KK];
#pragma unroll
    for (int k = 0; k < KK; ++k) dk_[k] = drow[k];
    float v[KK];
#pragma unroll
    for (int k = 0; k < KK; ++k) {
        float d = dk_[k];
        unsigned g = gvv[k];
        float t0 = fmaxf(fmaf(d, f8d<0>(g), sv.x), 0.f);
        float t1 = fmaxf(fmaf(d, f8d<1>(g), sv.y), 0.f);
        float t2 = fmaxf(fmaf(d, f8d<2>(g), sv.z), 0.f);
        float t3 = fmaxf(fmaf(d, f8d<3>(g), sv.w), 0.f);
        v[k] = t0 * wpv.x + t1 * wpv.y + t2 * wpv.z + t3 * wpv.w;
    }
#pragma unroll
    for (int sh = 1; sh < 32; sh <<= 1) {
#pragma unroll
        for (int k = 0; k < KK; ++k) v[k] += __shfl_xor(v[k], sh, 64);
    }
    float bpv = bp[0];
    float ss = 0.f;
#pragma unroll
    for (int k = 0; k < KK; ++k) { v[k] += bpv; ss = fmaf(v[k], v[k], ss); }
    float inv = 1.0f / fmaxf(sqrtf(ss), 1e-12f);
    float4 bl = *(const float4*)(blin + 4 * s);
    float a0 = bl.x, a1 = bl.y, a2 = bl.z, a3 = bl.w;
#pragma unroll
    for (int k = 0; k < KK; ++k) {
        float xv = fmaxf(v[k], 0.f) * inv;
        float4 wl = *(const float4*)(wlin + k * HH + 4 * s);
        a0 = fmaf(xv, wl.x, a0);
        a1 = fmaf(xv, wl.y, a1);
        a2 = fmaf(xv, wl.z, a2);
        a3 = fmaf(xv, wl.w, a3);
    }
    uint2 o;
    o.x = (unsigned)f2h(fmaxf(a0, 0.f)) | ((unsigned)f2h(fmaxf(a1, 0.f)) << 16);
    o.y = (unsigned)f2h(fmaxf(a2, 0.f)) | ((unsigned)f2h(fmaxf(a3, 0.f)) << 16);
    hlu2[(size_t)n * 32 + s] = o;
}

// ---------------- K7: ab = [hl@W1top | hl@W1bot + ff_b1] via MFMA (fp16 out) ----------------
__global__ __launch_bounds__(256) void k_ab_mfma(
    const unsigned short* __restrict__ hl16, const unsigned short* __restrict__ wt1,
    const float* __restrict__ ffb1, unsigned short* __restrict__ ab) {
    int t = threadIdx.x;
    int l = t & 63, w = t >> 6;
    int c = l & 31, kh = l >> 5;
    int nb = blockIdx.x * 32;
    int na = nb + c;
    if (na >= NN) na = NN - 1;
    fp16x8 af[8];
#pragma unroll
    for (int kt = 0; kt < 8; ++kt)
        af[kt] = *(const fp16x8*)(hl16 + na * 128 + kt * 16 + kh * 8);
    f32x16 acc[4];
#pragma unroll
    for (int g = 0; g < 4; ++g)
#pragma unroll
        for (int i = 0; i < 16; ++i) acc[g][i] = 0.f;
#pragma unroll
    for (int kt = 0; kt < 8; ++kt) {
#pragma unroll
        for (int g = 0; g < 4; ++g) {
            fp16x8 b = *(const fp16x8*)(wt1 + (w * 128 + g * 32 + c) * 128 + kt * 16 + kh * 8);
            acc[g] = __builtin_amdgcn_mfma_f32_32x32x16_f16(af[kt], b, acc[g], 0, 0, 0);
        }
    }
#pragma unroll
    for (int g = 0; g < 4; ++g) {
        int col = w * 128 + g * 32 + c;
        float bias = (col >= 256) ? ffb1[col - 256] : 0.f;
#pragma unroll
        for (int r = 0; r < 16; ++r) {
            int row = (r & 3) + 8 * (r >> 2) + 4 * kh;
            int n = nb + row;
            if (n < NN) ab[n * 512 + col] = f2h(acc[g][r] + bias);
        }
    }
}

// ---------------- K8: sorted edges, 32-edge tiles, 1 wave/block, 9 blocks/CU ----------------
// Single-wave blocks: no inter-wave barriers; 16 KB LDS -> 9 blocks/CU resident.
__global__ __launch_bounds__(64) void k_edge_mfma(
    const unsigned short* __restrict__ abf, const uint4* __restrict__ sedge,
    const unsigned short* __restrict__ wt, const float* __restrict__ ffb2,
    float* __restrict__ out) {
    __shared__ uint4 P[32 * 32];  // 16 KB: 32 rows x 256 fp16, swizzled
    int t = threadIdx.x;
    int c = t & 31, kh = t >> 5;

    fp16x8 wf0[16], wf1[16];
#pragma unroll
    for (int kt = 0; kt < 16; ++kt) {
        wf0[kt] = *(const fp16x8*)(wt + c * 256 + kt * 16 + kh * 8);
        wf1[kt] = *(const fp16x8*)(wt + (c + 32) * 256 + kt * 16 + kh * 8);
    }
    float bias0 = ffb2[c], bias1 = ffb2[c + 32];

    int xcd = blockIdx.x & 7;
    int slot = blockIdx.x >> 3;   // 0..287
    int seg = c;                  // 16B segment within a 512B row
    int rb = kh;                  // 0..1: row parity in staging

    for (int tl = slot; tl < NT32; tl += 288) {
        int tb = (xcd * NT32 + tl) * 32;
        // ---- stage 32 rows of relu(a+b), coalesced (2 rows per iter) ----
#pragma unroll 4
        for (int it = 0; it < 16; ++it) {
            int row = it * 2 + rb;
            int pos = tb + row;
            uint4 rec = sedge[pos < EE ? pos : EE - 1];
            uint4 a = *(const uint4*)(abf + (size_t)rec.x * 512 + seg * 8);
            uint4 b = *(const uint4*)(abf + (size_t)rec.y * 512 + 256 + seg * 8);
            uint4 p;
            p.x = hrelu2(a.x, b.x);
            p.y = hrelu2(a.y, b.y);
            p.z = hrelu2(a.z, b.z);
            p.w = hrelu2(a.w, b.w);
            int col = (seg * 16) ^ ((row & 15) << 4);
            P[row * 32 + (col >> 4)] = p;
        }
        __syncthreads();   // single-wave block: compiles to a waitcnt, no barrier stall
        f32x16 acc0, acc1;
#pragma unroll
        for (int i = 0; i < 16; ++i) { acc0[i] = 0.f; acc1[i] = 0.f; }
        int sw = (c & 15) << 4;
#pragma unroll
        for (int kt = 0; kt < 16; ++kt) {
            int col = (kt * 32 + kh * 16) ^ sw;
            fp16x8 af = __builtin_bit_cast(fp16x8, P[c * 32 + (col >> 4)]);
            acc0 = __builtin_amdgcn_mfma_f32_32x32x16_f16(af, wf0[kt], acc0, 0, 0, 0);
            acc1 = __builtin_amdgcn_mfma_f32_32x32x16_f16(af, wf1[kt], acc1, 0, 0, 0);
        }
        int spos = tb + c;
        int eid = (int)sedge[spos < EE ? spos : EE - 1].z;
        int rbase = 4 * kh;
#pragma unroll
        for (int r = 0; r < 16; ++r) {
            int row = (r & 3) + 8 * (r >> 2) + rbase;
            int eidr = __shfl(eid, row, 64);
            if (tb + row < EE) {
                size_t o = (size_t)eidr * 64;
                out[o + c] = acc0[r] + bias0;
                out[o + 32 + c] = acc1[r] + bias1;
            }
        }
        __syncthreads();
    }
}

extern "C" void kernel_launch(void* const* d_in, const int* in_sizes, int n_in,
                              void* d_out, int out_size, void* d_ws, size_t ws_size,
                              hipStream_t stream) {
    const float* x     = (const float*)d_in[0];
    const float* dmax  = (const float*)d_in[1];
    const int*   amax  = (const int*)d_in[2];
    const int*   ei    = (const int*)d_in[3];
    const float* w_pre = (const float*)d_in[5];
    const float* b_pre = (const float*)d_in[6];
    const float* l1w1  = (const float*)d_in[7];
    const float* l1b1  = (const float*)d_in[8];
    const float* l1w2  = (const float*)d_in[9];
    const float* l1b2  = (const float*)d_in[10];
    const float* l1wh  = (const float*)d_in[11];
    const float* l1bh  = (const float*)d_in[12];
    const float* l2w1  = (const float*)d_in[15];
    const float* l2b1  = (const float*)d_in[16];
    const float* l2w2  = (const float*)d_in[17];
    const float* l2b2  = (const float*)d_in[18];
    const float* l2wh  = (const float*)d_in[19];
    const float* l2bh  = (const float*)d_in[20];
    const float* l2wp  = (const float*)d_in[21];
    const float* l2bp  = (const float*)d_in[22];
    const float* wlin  = (const float*)d_in[23];
    const float* blin  = (const float*)d_in[24];
    const float* ffw1  = (const float*)d_in[25];
    const float* ffb1  = (const float*)d_in[26];
    const float* ffw2  = (const float*)d_in[27];
    const float* ffb2  = (const float*)d_in[28];

    float* ws = (float*)d_ws;
    unsigned char* Gb8 = (unsigned char*)(ws + 1500000);   // 3.84 MB fp8 table
    float* S  = ws + 3500000;
    unsigned short* xh = (unsigned short*)(ws + 7500000);
    unsigned short* xl = (unsigned short*)(ws + 8500000);
    unsigned* hhp = (unsigned*)(ws + 9500000);
    unsigned* hlp = (unsigned*)(ws + 11500000);
    unsigned short* hl16 = (unsigned short*)(ws + 13500000);
    uint4* sedge = (uint4*)(ws + 15500000);
    unsigned short* wfh = (unsigned short*)(ws + 17500000);
    unsigned short* wfl = (unsigned short*)(ws + 17510000);
    float* bfuse = ws + 17520000;
    unsigned short* wt = (unsigned short*)(ws + 17530000);
    unsigned short* wt1 = (unsigned short*)(ws + 17540000);
    unsigned short* wt2h = (unsigned short*)(ws + 17580000);
    unsigned short* wt2l = (unsigned short*)(ws + 17600000);
    unsigned* hist = (unsigned*)(ws + 17620000);
    unsigned* cursor = (unsigned*)(ws + 17630000);
    float* lut1 = ws + 17640000;
    float* lut2 = ws + 17645000;
    float* d1 = ws + 18000000;
    float* d2 = ws + 18750000;
    unsigned short* ab = (unsigned short*)ws;
    float* out = (float*)d_out;

    // Fused prep: hist-zero + d-MLP LUTs + x split-fp16 + weight tables
    k_prep<<<1498, 256, 0, stream>>>(x, w_pre, b_pre, l1wh, l1bh, ffw2, ffw1, l2wh,
                                     l1w1, l1b1, l1w2, l1b2, l2w1, l2b1, l2w2, l2b2,
                                     hist, lut1, lut2, xh, xl,
                                     bfuse, wt, wt1, wt2h, wt2l, wfh, wfl);
    // Fused: d1,d2 LUT eval + edge histogram
    k_dlut_hist<<<(DL_N + EE / 8 + 255) / 256, 256, 0, stream>>>(
        dmax, lut1, lut2, d1, d2, ei, hist);

    // Node pipeline (scan fused into nodegemm<IN_F>; scatter fused into layer1)
    k_nodegemm<IN_F><<<939, 256, 0, stream>>>(xh, xl, wfh, wfl, bfuse, bfuse + 128,
                                              Gb8, S, hist, cursor, 938);
    k_layer1<<<L1BLK + SCBLK, 256, 0, stream>>>((const unsigned*)Gb8, S, d1, amax,
                                                (uint2*)hhp, (uint2*)hlp,
                                                ei, cursor, sedge);
    k_nodegemm<HH><<<938, 256, 0, stream>>>((const unsigned short*)hhp,
                                            (const unsigned short*)hlp, wt2h, wt2l,
                                            nullptr, l2bh, Gb8, S,
                                            nullptr, nullptr, 938);
    k_xpos2<<<NN / 8, 256, 0, stream>>>((const unsigned*)Gb8, S, d2, amax,
                                        l2wp, l2bp, wlin, blin, (uint2*)hl16);
    k_ab_mfma<<<938, 256, 0, stream>>>(hl16, wt1, ffb1, ab);

    // Sorted, XCD-pinned edge GEMM: 32-edge tiles, 1 wave/block, 9 blocks/CU
    k_edge_mfma<<<2304, 64, 0, stream>>>(ab, sedge, wt, ffb2, out);
}

// Round 21
// 291.488 us; speedup vs baseline: 1.0604x; 1.0604x over previous
//
#include <hip/hip_runtime.h>
#include <hip/hip_bf16.h>
#include <hip/hip_fp8.h>
#include <cmath>

#define NN 30000
#define KK 25
#define IN_F 64
#define FEAT 32
#define HH 128
#define OUTF 64
#define EE 480000
#define NPAGE 469              // dst pages of 64 nodes
#define NB (8 * NPAGE)         // sort buckets
#define LUTN 4096
#define NT64 938               // 64-edge tiles per XCD (8*938*64 = 480256 >= EE)
#define L1BLK (NN / 8)         // 3750 layer1 node blocks
#define SCBLK ((EE / 8 + 255) / 256)  // 235 scatter blocks fused into layer1

typedef __attribute__((ext_vector_type(8))) _Float16 fp16x8;
typedef __attribute__((ext_vector_type(2))) _Float16 h2v;
typedef __attribute__((ext_vector_type(16))) float f32x16;

__device__ inline float u2f(unsigned u) { return __builtin_bit_cast(float, u); }
__device__ inline unsigned short f2h(float f) {
    _Float16 h = (_Float16)f;
    return __builtin_bit_cast(unsigned short, h);
}
__device__ inline float blo(unsigned u) { return u2f(u << 16); }
__device__ inline float bhi(unsigned u) { return u2f(u & 0xffff0000u); }

// fp8 e4m3 (OCP) encode/decode — HW paths on gfx950
__device__ inline unsigned char f2f8(float v) {
    __hip_fp8_e4m3 h(v);
    return (unsigned char)h.__x;
}
template <int S0>
__device__ inline float f8d(unsigned u) {
    return __builtin_amdgcn_cvt_f32_fp8(u, S0);
}

// packed fp16: relu(a + b) on 2 lanes
__device__ inline unsigned hrelu2(unsigned a, unsigned b) {
    h2v x = __builtin_bit_cast(h2v, a);
    h2v y = __builtin_bit_cast(h2v, b);
    h2v s = x + y;
    h2v z = {(_Float16)0.f, (_Float16)0.f};
    h2v r = __builtin_elementwise_max(s, z);
    return __builtin_bit_cast(unsigned, r);
}

__device__ inline float lut_eval(const float* __restrict__ lut, float dm) {
    float tt = dm * (float)LUTN;
    int i0 = (int)tt;
    i0 = i0 < 0 ? 0 : (i0 > LUTN - 1 ? LUTN - 1 : i0);
    float f = tt - (float)i0;
    float l0 = lut[i0];
    return fmaf(lut[i0 + 1] - l0, f, l0);
}

// ---------------- K0: fused prep ----------------
__global__ void k_prep(const float* __restrict__ x,
                       const float* __restrict__ w_pre, const float* __restrict__ b_pre,
                       const float* __restrict__ l1wh, const float* __restrict__ l1bh,
                       const float* __restrict__ ffw2, const float* __restrict__ ffw1,
                       const float* __restrict__ l2wh,
                       const float* __restrict__ l1w1, const float* __restrict__ l1b1,
                       const float* __restrict__ l1w2, const float* __restrict__ l1b2,
                       const float* __restrict__ l2w1, const float* __restrict__ l2b1,
                       const float* __restrict__ l2w2, const float* __restrict__ l2b2,
                       unsigned* __restrict__ hist,
                       float* __restrict__ lut1, float* __restrict__ lut2,
                       unsigned short* __restrict__ xh, unsigned short* __restrict__ xl,
                       float* __restrict__ bfuse, unsigned short* __restrict__ wt,
                       unsigned short* __restrict__ wt1,
                       unsigned short* __restrict__ wt2h, unsigned short* __restrict__ wt2l,
                       unsigned short* __restrict__ wfh, unsigned short* __restrict__ wfl) {
    int gid = blockIdx.x * 256 + threadIdx.x;
    if (gid < NB) { hist[gid] = 0u; return; }
    gid -= NB;
    if (gid < 2 * (LUTN + 1)) {
        int which = gid / (LUTN + 1);
        int i = gid % (LUTN + 1);
        float dm = (float)i * (1.0f / (float)LUTN);
        const float* w1 = which ? l2w1 : l1w1;
        const float* b1 = which ? l2b1 : l1b1;
        const float* w2 = which ? l2w2 : l1w2;
        const float* b2 = which ? l2b2 : l1b2;
        float a = 0.f;
        for (int h = 0; h < HH; ++h)
            a = fmaf(fmaxf(fmaf(dm, w1[h], b1[h]), 0.f), w2[h], a);
        (which ? lut2 : lut1)[i] = a + b2[0];
        return;
    }
    gid -= 2 * (LUTN + 1);
    if (gid < NN * IN_F / 8) {
        int i = gid * 8;
        unsigned short vh[8], vl[8];
#pragma unroll
        for (int j = 0; j < 8; ++j) {
            float v = x[i + j];
            _Float16 hi = (_Float16)v;
            vh[j] = __builtin_bit_cast(unsigned short, hi);
            vl[j] = f2h((v - (float)hi) * 1024.f);
        }
        *(uint4*)(xh + i) = *(uint4*)vh;
        *(uint4*)(xl + i) = *(uint4*)vl;
        return;
    }
    gid -= NN * IN_F / 8;
    if (gid < 256) {
        int half = gid >> 7, h = gid & 127;
        const float* wh = l1wh + half * FEAT * HH + h;
        float acc = (half == 1) ? l1bh[h] : 0.f;
#pragma unroll
        for (int c = 0; c < FEAT; ++c) acc = fmaf(b_pre[c], wh[c * HH], acc);
        bfuse[gid] = acc;
    } else if (gid < 16640) {
        int i = gid - 256;
        int k = i >> 6, c = i & 63;
        wt[c * 256 + k] = f2h(ffw2[i]);
    } else if (gid < 82176) {
        int i = gid - 16640;
        int c = i >> 7, j = i & 127;
        float v = (c < 256) ? ffw1[j * 256 + c] : ffw1[(128 + j) * 256 + (c - 256)];
        wt1[c * 128 + j] = f2h(v);
    } else if (gid < 114944) {
        int i = gid - 82176;
        int c = i >> 7, j = i & 127;
        float v = (c < 128) ? l2wh[j * 128 + c] : l2wh[(128 + j) * 128 + (c - 128)];
        _Float16 hi = (_Float16)v;
        wt2h[c * 128 + j] = __builtin_bit_cast(unsigned short, hi);
        wt2l[c * 128 + j] = f2h((v - (float)hi) * 1024.f);
    } else if (gid < 131328) {
        int i = gid - 114944;
        int cc = i >> 6, j = i & 63;
        const float* wrow = w_pre + j * FEAT;
        float acc = 0.f;
#pragma unroll
        for (int c = 0; c < FEAT; ++c) {
            float wh = (cc < 128) ? l1wh[c * HH + cc] : l1wh[(FEAT + c) * HH + (cc - 128)];
            acc = fmaf(wrow[c], wh, acc);
        }
        _Float16 hi = (_Float16)acc;
        wfh[cc * 64 + j] = __builtin_bit_cast(unsigned short, hi);
        wfl[cc * 64 + j] = f2h((acc - (float)hi) * 1024.f);
    }
}

// ---------------- K0b: fused d-LUT eval + edge histogram ----------------
#define DL_N (NN * KK / 4)
__global__ void k_dlut_hist(const float* __restrict__ dmax, const float* __restrict__ lut1,
                            const float* __restrict__ lut2,
                            float* __restrict__ d1, float* __restrict__ d2,
                            const int* __restrict__ ei, unsigned* __restrict__ hist) {
    int gid = blockIdx.x * 256 + threadIdx.x;
    if (gid < DL_N) {
        int i = gid * 4;
        float4 dm = *(const float4*)(dmax + i);
        float4 o1, o2;
        o1.x = lut_eval(lut1, dm.x); o1.y = lut_eval(lut1, dm.y);
        o1.z = lut_eval(lut1, dm.z); o1.w = lut_eval(lut1, dm.w);
        o2.x = lut_eval(lut2, dm.x); o2.y = lut_eval(lut2, dm.y);
        o2.z = lut_eval(lut2, dm.z); o2.w = lut_eval(lut2, dm.w);
        *(float4*)(d1 + i) = o1;
        *(float4*)(d2 + i) = o2;
        return;
    }
    int base = (gid - DL_N) * 8;
    if (base >= EE) return;
    int4 s0 = *(const int4*)(ei + base);
    int4 s1 = *(const int4*)(ei + base + 4);
    int4 dd0 = *(const int4*)(ei + EE + base);
    int4 dd1 = *(const int4*)(ei + EE + base + 4);
    int ss[8] = {s0.x, s0.y, s0.z, s0.w, s1.x, s1.y, s1.z, s1.w};
    int dd[8] = {dd0.x, dd0.y, dd0.z, dd0.w, dd1.x, dd1.y, dd1.z, dd1.w};
#pragma unroll
    for (int j = 0; j < 8; ++j) {
        int key = (ss[j] * 8 / NN) * NPAGE + (dd[j] >> 6);
        atomicAdd(&hist[key], 1u);
    }
}

// ---------------- Unified node GEMM via split-fp16 MFMA; G out = fp8 e4m3 ----------------
// For the IN_F instantiation, one extra block (blockIdx == nodeBlocks) runs the
// single-wave hist->cursor scan (hist != nullptr), fusing k_scan's dispatch away.
template <int KD>
__global__ __launch_bounds__(256) void k_nodegemm(
    const unsigned short* __restrict__ Ah, const unsigned short* __restrict__ Al,
    const unsigned short* __restrict__ Wh, const unsigned short* __restrict__ Wl,
    const float* __restrict__ gbias, const float* __restrict__ sbias,
    unsigned char* __restrict__ Gb8, float* __restrict__ S,
    const unsigned* __restrict__ hist, unsigned* __restrict__ cursor, int nodeBlocks) {
    if (hist && blockIdx.x >= (unsigned)nodeBlocks) {
        // ---- fused scan (single wave) ----
        int l = threadIdx.x;
        if (l >= 64) return;
        const int PER = 59;
        unsigned tot = 0;
        for (int j = 0; j < PER; ++j) {
            int i = l * PER + j;
            if (i < NB) tot += hist[i];
        }
        unsigned run = tot;
#pragma unroll
        for (int off = 1; off < 64; off <<= 1) {
            unsigned u = __shfl_up(run, off, 64);
            if (l >= off) run += u;
        }
        unsigned base = run - tot;
        for (int j = 0; j < PER; ++j) {
            int i = l * PER + j;
            if (i < NB) {
                cursor[i] = base;
                base += hist[i];
            }
        }
        return;
    }
    int t = threadIdx.x;
    int l = t & 63, w = t >> 6;
    int c = l & 31, kh = l >> 5;
    int nb = blockIdx.x * 32;
    int na = nb + c;
    if (na >= NN) na = NN - 1;
    fp16x8 afh[KD / 16], afl[KD / 16];
#pragma unroll
    for (int kt = 0; kt < KD / 16; ++kt) {
        afh[kt] = *(const fp16x8*)(Ah + na * KD + kt * 16 + kh * 8);
        afl[kt] = *(const fp16x8*)(Al + na * KD + kt * 16 + kh * 8);
    }
    f32x16 acch0, acch1, accl0, accl1;
#pragma unroll
    for (int i = 0; i < 16; ++i) { acch0[i] = 0.f; acch1[i] = 0.f; accl0[i] = 0.f; accl1[i] = 0.f; }
    int cb0 = w * 64, cb1 = w * 64 + 32;
#pragma unroll
    for (int kt = 0; kt < KD / 16; ++kt) {
        fp16x8 b0h = *(const fp16x8*)(Wh + (cb0 + c) * KD + kt * 16 + kh * 8);
        fp16x8 b0l = *(const fp16x8*)(Wl + (cb0 + c) * KD + kt * 16 + kh * 8);
        fp16x8 b1h = *(const fp16x8*)(Wh + (cb1 + c) * KD + kt * 16 + kh * 8);
        fp16x8 b1l = *(const fp16x8*)(Wl + (cb1 + c) * KD + kt * 16 + kh * 8);
        acch0 = __builtin_amdgcn_mfma_f32_32x32x16_f16(afh[kt], b0h, acch0, 0, 0, 0);
        accl0 = __builtin_amdgcn_mfma_f32_32x32x16_f16(afh[kt], b0l, accl0, 0, 0, 0);
        accl0 = __builtin_amdgcn_mfma_f32_32x32x16_f16(afl[kt], b0h, accl0, 0, 0, 0);
        acch1 = __builtin_amdgcn_mfma_f32_32x32x16_f16(afh[kt], b1h, acch1, 0, 0, 0);
        accl1 = __builtin_amdgcn_mfma_f32_32x32x16_f16(afh[kt], b1l, accl1, 0, 0, 0);
        accl1 = __builtin_amdgcn_mfma_f32_32x32x16_f16(afl[kt], b1h, accl1, 0, 0, 0);
    }
    const float inv1024 = 1.0f / 1024.0f;
#pragma unroll
    for (int half = 0; half < 2; ++half) {
        int col = (half ? cb1 : cb0) + c;
        bool isG = col < HH;
        float gb_ = (isG && gbias) ? gbias[col] : 0.f;
        float sb_ = (!isG) ? sbias[col - HH] : 0.f;
#pragma unroll
        for (int r = 0; r < 16; ++r) {
            int row = (r & 3) + 8 * (r >> 2) + 4 * kh;
            int n = nb + row;
            float v = half ? (acch1[r] + accl1[r] * inv1024)
                           : (acch0[r] + accl0[r] * inv1024);
            if (n < NN) {
                if (isG) Gb8[n * HH + col] = f2f8(v + gb_);
                else S[n * HH + (col - HH)] = v + sb_;
            }
        }
    }
}

// ---------------- K4: layer1, 2 nodes/WAVE, fp8 G gathers; fused edge scatter ----------------
// Blocks >= L1BLK run the edge-sort scatter (cursor ready: scan ran in the
// preceding k_nodegemm<IN_F> dispatch).
__global__ void k_layer1(const unsigned* __restrict__ G8, const float* __restrict__ S1,
                         const float* __restrict__ d1, const int* __restrict__ amax,
                         uint2* __restrict__ hh, uint2* __restrict__ hl,
                         const int* __restrict__ ei, unsigned* __restrict__ cursor,
                         uint4* __restrict__ sedge) {
    if (blockIdx.x >= L1BLK) {
        // ---- fused scatter ----
        int base = ((blockIdx.x - L1BLK) * 256 + threadIdx.x) * 8;
        if (base >= EE) return;
        int4 s0 = *(const int4*)(ei + base);
        int4 s1 = *(const int4*)(ei + base + 4);
        int4 d0 = *(const int4*)(ei + EE + base);
        int4 dd1 = *(const int4*)(ei + EE + base + 4);
        int ss[8] = {s0.x, s0.y, s0.z, s0.w, s1.x, s1.y, s1.z, s1.w};
        int dd[8] = {d0.x, d0.y, d0.z, d0.w, dd1.x, dd1.y, dd1.z, dd1.w};
        unsigned pp[8];
#pragma unroll
        for (int j = 0; j < 8; ++j) {
            int key = (ss[j] * 8 / NN) * NPAGE + (dd[j] >> 6);
            pp[j] = atomicAdd(&cursor[key], 1u);
        }
#pragma unroll
        for (int j = 0; j < 8; ++j)
            sedge[pp[j]] = make_uint4((unsigned)ss[j], (unsigned)dd[j], (unsigned)(base + j), 0u);
        return;
    }
    int t = threadIdx.x;
    int s = t & 31;
    int n = blockIdx.x * 8 + (t >> 5);
    float4 sv = *(const float4*)(S1 + n * HH + 4 * s);
    const int* arow = amax + n * KK;
    const float* drow = d1 + n * KK;
    unsigned gvv[KK];
#pragma unroll
    for (int k = 0; k < KK; ++k) gvv[k] = G8[(size_t)arow[k] * 32 + s];
    float dk_[KK];
#pragma unroll
    for (int k = 0; k < KK; ++k) dk_[k] = drow[k];
    float a0 = 0.f, a1 = 0.f, a2 = 0.f, a3 = 0.f;
#pragma unroll
    for (int k = 0; k < KK; ++k) {
        float d = dk_[k];
        unsigned g = gvv[k];
        a0 += fmaxf(fmaf(d, f8d<0>(g), sv.x), 0.f);
        a1 += fmaxf(fmaf(d, f8d<1>(g), sv.y), 0.f);
        a2 += fmaxf(fmaf(d, f8d<2>(g), sv.z), 0.f);
        a3 += fmaxf(fmaf(d, f8d<3>(g), sv.w), 0.f);
    }
    a0 *= 0.04f; a1 *= 0.04f; a2 *= 0.04f; a3 *= 0.04f;
    _Float16 h0 = (_Float16)a0, h1v = (_Float16)a1, h2v_ = (_Float16)a2, h3 = (_Float16)a3;
    uint2 oh, ol;
    oh.x = (unsigned)__builtin_bit_cast(unsigned short, h0) |
           ((unsigned)__builtin_bit_cast(unsigned short, h1v) << 16);
    oh.y = (unsigned)__builtin_bit_cast(unsigned short, h2v_) |
           ((unsigned)__builtin_bit_cast(unsigned short, h3) << 16);
    ol.x = (unsigned)f2h((a0 - (float)h0) * 1024.f) |
           ((unsigned)f2h((a1 - (float)h1v) * 1024.f) << 16);
    ol.y = (unsigned)f2h((a2 - (float)h2v_) * 1024.f) |
           ((unsigned)f2h((a3 - (float)h3) * 1024.f) << 16);
    hh[(size_t)n * 32 + s] = oh;
    hl[(size_t)n * 32 + s] = ol;
}

// ---------------- K6: layer2, 2 nodes/WAVE, fp8 G gathers ----------------
__global__ __launch_bounds__(256) void k_xpos2(
    const unsigned* __restrict__ G8, const float* __restrict__ S2,
    const float* __restrict__ d2, const int* __restrict__ amax,
    const float* __restrict__ wp, const float* __restrict__ bp,
    const float* __restrict__ wlin, const float* __restrict__ blin,
    uint2* __restrict__ hlu2) {
    int t = threadIdx.x;
    int s = t & 31;
    int n = blockIdx.x * 8 + (t >> 5);
    float4 sv = *(const float4*)(S2 + n * HH + 4 * s);
    float4 wpv = *(const float4*)(wp + 4 * s);
    const int* arow = amax + n * KK;
    const float* drow = d2 + n * KK;
    unsigned gvv[KK];
#pragma unroll
    for (int k = 0; k < KK; ++k) gvv[k] = G8[(size_t)arow[k] * 32 + s];
    float dk_[KK];
#pragma unroll
    for (int k = 0; k < KK; ++k) dk_[k] = drow[k];
    float v[KK];
#pragma unroll
    for (int k = 0; k < KK; ++k) {
        float d = dk_[k];
        unsigned g = gvv[k];
        float t0 = fmaxf(fmaf(d, f8d<0>(g), sv.x), 0.f);
        float t1 = fmaxf(fmaf(d, f8d<1>(g), sv.y), 0.f);
        float t2 = fmaxf(fmaf(d, f8d<2>(g), sv.z), 0.f);
        float t3 = fmaxf(fmaf(d, f8d<3>(g), sv.w), 0.f);
        v[k] = t0 * wpv.x + t1 * wpv.y + t2 * wpv.z + t3 * wpv.w;
    }
#pragma unroll
    for (int sh = 1; sh < 32; sh <<= 1) {
#pragma unroll
        for (int k = 0; k < KK; ++k) v[k] += __shfl_xor(v[k], sh, 64);
    }
    float bpv = bp[0];
    float ss = 0.f;
#pragma unroll
    for (int k = 0; k < KK; ++k) { v[k] += bpv; ss = fmaf(v[k], v[k], ss); }
    float inv = 1.0f / fmaxf(sqrtf(ss), 1e-12f);
    float4 bl = *(const float4*)(blin + 4 * s);
    float a0 = bl.x, a1 = bl.y, a2 = bl.z, a3 = bl.w;
#pragma unroll
    for (int k = 0; k < KK; ++k) {
        float xv = fmaxf(v[k], 0.f) * inv;
        float4 wl = *(const float4*)(wlin + k * HH + 4 * s);
        a0 = fmaf(xv, wl.x, a0);
        a1 = fmaf(xv, wl.y, a1);
        a2 = fmaf(xv, wl.z, a2);
        a3 = fmaf(xv, wl.w, a3);
    }
    uint2 o;
    o.x = (unsigned)f2h(fmaxf(a0, 0.f)) | ((unsigned)f2h(fmaxf(a1, 0.f)) << 16);
    o.y = (unsigned)f2h(fmaxf(a2, 0.f)) | ((unsigned)f2h(fmaxf(a3, 0.f)) << 16);
    hlu2[(size_t)n * 32 + s] = o;
}

// ---------------- K7: ab = [hl@W1top | hl@W1bot + ff_b1] via MFMA (fp16 out) ----------------
__global__ __launch_bounds__(256) void k_ab_mfma(
    const unsigned short* __restrict__ hl16, const unsigned short* __restrict__ wt1,
    const float* __restrict__ ffb1, unsigned short* __restrict__ ab) {
    int t = threadIdx.x;
    int l = t & 63, w = t >> 6;
    int c = l & 31, kh = l >> 5;
    int nb = blockIdx.x * 32;
    int na = nb + c;
    if (na >= NN) na = NN - 1;
    fp16x8 af[8];
#pragma unroll
    for (int kt = 0; kt < 8; ++kt)
        af[kt] = *(const fp16x8*)(hl16 + na * 128 + kt * 16 + kh * 8);
    f32x16 acc[4];
#pragma unroll
    for (int g = 0; g < 4; ++g)
#pragma unroll
        for (int i = 0; i < 16; ++i) acc[g][i] = 0.f;
#pragma unroll
    for (int kt = 0; kt < 8; ++kt) {
#pragma unroll
        for (int g = 0; g < 4; ++g) {
            fp16x8 b = *(const fp16x8*)(wt1 + (w * 128 + g * 32 + c) * 128 + kt * 16 + kh * 8);
            acc[g] = __builtin_amdgcn_mfma_f32_32x32x16_f16(af[kt], b, acc[g], 0, 0, 0);
        }
    }
#pragma unroll
    for (int g = 0; g < 4; ++g) {
        int col = w * 128 + g * 32 + c;
        float bias = (col >= 256) ? ffb1[col - 256] : 0.f;
#pragma unroll
        for (int r = 0; r < 16; ++r) {
            int row = (r & 3) + 8 * (r >> 2) + 4 * kh;
            int n = nb + row;
            if (n < NN) ab[n * 512 + col] = f2h(acc[g][r] + bias);
        }
    }
}

// ---------------- K8: sorted edges, 64-edge tiles, grid=4 blocks/CU (measured-best) ----------------
__global__ __launch_bounds__(128, 2) void k_edge_mfma(
    const unsigned short* __restrict__ abf, const uint4* __restrict__ sedge,
    const unsigned short* __restrict__ wt, const float* __restrict__ ffb2,
    float* __restrict__ out) {
    __shared__ uint4 P[64 * 32];  // 32 KB: 64 rows x 256 fp16, swizzled
    int t = threadIdx.x;
    int l = t & 63;
    int w = t >> 6;
    int c = l & 31, kh = l >> 5;

    fp16x8 wf0[16], wf1[16];
#pragma unroll
    for (int kt = 0; kt < 16; ++kt) {
        wf0[kt] = *(const fp16x8*)(wt + c * 256 + kt * 16 + kh * 8);
        wf1[kt] = *(const fp16x8*)(wt + (c + 32) * 256 + kt * 16 + kh * 8);
    }
    float bias0 = ffb2[c], bias1 = ffb2[c + 32];

    int xcd = blockIdx.x & 7;
    int slot = blockIdx.x >> 3;
    int seg = t & 31;
    int rb = t >> 5;

    for (int tl = slot; tl < NT64; tl += 128) {
        int tb = (xcd * NT64 + tl) * 64;
#pragma unroll 4
        for (int it = 0; it < 16; ++it) {
            int row = it * 4 + rb;
            int pos = tb + row;
            uint4 rec = sedge[pos < EE ? pos : EE - 1];
            uint4 a = *(const uint4*)(abf + (size_t)rec.x * 512 + seg * 8);
            uint4 b = *(const uint4*)(abf + (size_t)rec.y * 512 + 256 + seg * 8);
            uint4 p;
            p.x = hrelu2(a.x, b.x);
            p.y = hrelu2(a.y, b.y);
            p.z = hrelu2(a.z, b.z);
            p.w = hrelu2(a.w, b.w);
            int col = (seg * 16) ^ ((row & 15) << 4);
            P[row * 32 + (col >> 4)] = p;
        }
        __syncthreads();
        f32x16 acc0, acc1;
#pragma unroll
        for (int i = 0; i < 16; ++i) { acc0[i] = 0.f; acc1[i] = 0.f; }
        int wrow = w * 32 + c;
        int sw = (wrow & 15) << 4;
#pragma unroll
        for (int kt = 0; kt < 16; ++kt) {
            int col = (kt * 32 + kh * 16) ^ sw;
            fp16x8 af = __builtin_bit_cast(fp16x8, P[wrow * 32 + (col >> 4)]);
            acc0 = __builtin_amdgcn_mfma_f32_32x32x16_f16(af, wf0[kt], acc0, 0, 0, 0);
            acc1 = __builtin_amdgcn_mfma_f32_32x32x16_f16(af, wf1[kt], acc1, 0, 0, 0);
        }
        int spos = tb + wrow;
        int eid = (int)sedge[spos < EE ? spos : EE - 1].z;
        int rbase = 4 * kh;
#pragma unroll
        for (int r = 0; r < 16; ++r) {
            int row = (r & 3) + 8 * (r >> 2) + rbase;
            int eidr = __shfl(eid, row, 64);
            if (tb + w * 32 + row < EE) {
                size_t o = (size_t)eidr * 64;
                out[o + c] = acc0[r] + bias0;
                out[o + 32 + c] = acc1[r] + bias1;
            }
        }
        __syncthreads();
    }
}

extern "C" void kernel_launch(void* const* d_in, const int* in_sizes, int n_in,
                              void* d_out, int out_size, void* d_ws, size_t ws_size,
                              hipStream_t stream) {
    const float* x     = (const float*)d_in[0];
    const float* dmax  = (const float*)d_in[1];
    const int*   amax  = (const int*)d_in[2];
    const int*   ei    = (const int*)d_in[3];
    const float* w_pre = (const float*)d_in[5];
    const float* b_pre = (const float*)d_in[6];
    const float* l1w1  = (const float*)d_in[7];
    const float* l1b1  = (const float*)d_in[8];
    const float* l1w2  = (const float*)d_in[9];
    const float* l1b2  = (const float*)d_in[10];
    const float* l1wh  = (const float*)d_in[11];
    const float* l1bh  = (const float*)d_in[12];
    const float* l2w1  = (const float*)d_in[15];
    const float* l2b1  = (const float*)d_in[16];
    const float* l2w2  = (const float*)d_in[17];
    const float* l2b2  = (const float*)d_in[18];
    const float* l2wh  = (const float*)d_in[19];
    const float* l2bh  = (const float*)d_in[20];
    const float* l2wp  = (const float*)d_in[21];
    const float* l2bp  = (const float*)d_in[22];
    const float* wlin  = (const float*)d_in[23];
    const float* blin  = (const float*)d_in[24];
    const float* ffw1  = (const float*)d_in[25];
    const float* ffb1  = (const float*)d_in[26];
    const float* ffw2  = (const float*)d_in[27];
    const float* ffb2  = (const float*)d_in[28];

    float* ws = (float*)d_ws;
    unsigned char* Gb8 = (unsigned char*)(ws + 1500000);   // 3.84 MB fp8 table
    float* S  = ws + 3500000;
    unsigned short* xh = (unsigned short*)(ws + 7500000);
    unsigned short* xl = (unsigned short*)(ws + 8500000);
    unsigned* hhp = (unsigned*)(ws + 9500000);
    unsigned* hlp = (unsigned*)(ws + 11500000);
    unsigned short* hl16 = (unsigned short*)(ws + 13500000);
    uint4* sedge = (uint4*)(ws + 15500000);
    unsigned short* wfh = (unsigned short*)(ws + 17500000);
    unsigned short* wfl = (unsigned short*)(ws + 17510000);
    float* bfuse = ws + 17520000;
    unsigned short* wt = (unsigned short*)(ws + 17530000);
    unsigned short* wt1 = (unsigned short*)(ws + 17540000);
    unsigned short* wt2h = (unsigned short*)(ws + 17580000);
    unsigned short* wt2l = (unsigned short*)(ws + 17600000);
    unsigned* hist = (unsigned*)(ws + 17620000);
    unsigned* cursor = (unsigned*)(ws + 17630000);
    float* lut1 = ws + 17640000;
    float* lut2 = ws + 17645000;
    float* d1 = ws + 18000000;
    float* d2 = ws + 18750000;
    unsigned short* ab = (unsigned short*)ws;
    float* out = (float*)d_out;

    // Fused prep: hist-zero + d-MLP LUTs + x split-fp16 + weight tables
    k_prep<<<1498, 256, 0, stream>>>(x, w_pre, b_pre, l1wh, l1bh, ffw2, ffw1, l2wh,
                                     l1w1, l1b1, l1w2, l1b2, l2w1, l2b1, l2w2, l2b2,
                                     hist, lut1, lut2, xh, xl,
                                     bfuse, wt, wt1, wt2h, wt2l, wfh, wfl);
    // Fused: d1,d2 LUT eval + edge histogram
    k_dlut_hist<<<(DL_N + EE / 8 + 255) / 256, 256, 0, stream>>>(
        dmax, lut1, lut2, d1, d2, ei, hist);

    // Node pipeline (scan fused into nodegemm<IN_F> as block 938;
    // scatter fused into layer1 as blocks >= L1BLK)
    k_nodegemm<IN_F><<<939, 256, 0, stream>>>(xh, xl, wfh, wfl, bfuse, bfuse + 128,
                                              Gb8, S, hist, cursor, 938);
    k_layer1<<<L1BLK + SCBLK, 256, 0, stream>>>((const unsigned*)Gb8, S, d1, amax,
                                                (uint2*)hhp, (uint2*)hlp,
                                                ei, cursor, sedge);
    k_nodegemm<HH><<<938, 256, 0, stream>>>((const unsigned short*)hhp,
                                            (const unsigned short*)hlp, wt2h, wt2l,
                                            nullptr, l2bh, Gb8, S,
                                            nullptr, nullptr, 938);
    k_xpos2<<<NN / 8, 256, 0, stream>>>((const unsigned*)Gb8, S, d2, amax,
                                        l2wp, l2bp, wlin, blin, (uint2*)hl16);
    k_ab_mfma<<<938, 256, 0, stream>>>(hl16, wt1, ffb1, ab);

    // Sorted, XCD-pinned, LDS-staged edge GEMM (4 blocks/CU)
    k_edge_mfma<<<1024, 128, 0, stream>>>(ab, sedge, wt, ffb2, out);
}